// Round 8
// baseline (185.475 us; speedup 1.0000x reference)
//
#include <hip/hip_runtime.h>
#include <hip/hip_bf16.h>
#include <hip/hip_cooperative_groups.h>

namespace cg = cooperative_groups;

// Fixed shape: B=4096, I=1024, H=1024
#define B_ROWS 4096
#define H_DIM  1024
#define K_DIM  2048   // I + H
#define N_DIM  4096   // 4H
#define NT32   64     // K_DIM / 32 K-tiles

typedef __attribute__((ext_vector_type(8))) short bf16x8;
typedef __attribute__((ext_vector_type(4))) float f32x4;

__device__ __forceinline__ unsigned short f2bf(float f) {
  union { float f; unsigned int u; } v; v.f = f;
  unsigned int u = v.u;
  return (unsigned short)((u + 0x7fffu + ((u >> 16) & 1u)) >> 16);
}
__device__ __forceinline__ float bf2f(unsigned short u) {
  union { unsigned int u; float f; } v; v.u = ((unsigned int)u) << 16;
  return v.f;
}

__device__ __forceinline__ void gload_lds16(const void* g, void* l) {
  __builtin_amdgcn_global_load_lds(
      (const __attribute__((address_space(1))) void*)g,
      (__attribute__((address_space(3))) void*)l, 16, 0, 0);
}

__device__ __forceinline__ float sigmoidf_(float x) {
  return 1.0f / (1.0f + __expf(-x));
}
__device__ __forceinline__ float tanhf_(float x) {
  return 1.0f - 2.0f / (__expf(2.0f * x) + 1.0f);
}

struct KParams {
  const float *x, *h, *c, *W, *bias;
  const float *gi, *bi2, *gf, *bf2, *gg, *bg2, *go, *bo2, *gc, *bc2;
  unsigned short *Abf, *Wbf, *gates;
  float *out;
};

#define UNR _Pragma("unroll")

// Stage one K32-tile chunk for this wave: A rows 32w..+31, B rows 32w..+31
#define PSTG(kt, BUFOFS)                                                     \
  {                                                                          \
    const size_t ko = (size_t)(kt) << 5;                                     \
    char* const Ld = lds + (BUFOFS);                                         \
    gload_lds16(gAw + ko, Ld + dstOfs);                                      \
    gload_lds16(gAw + ko + 16 * K_DIM, Ld + dstOfs + 1024);                  \
    gload_lds16(gBw + ko, Ld + 16384 + dstOfs);                              \
    gload_lds16(gBw + ko + 16 * K_DIM, Ld + 16384 + dstOfs + 1024);          \
  }

// One K32-tile: stage(t+3) -> vmcnt(8) -> barrier -> lgkmcnt(0) ->
// interleaved { 12 ds_read frags(t+1) | 32 MFMA on frags(t) } via
// sched_group_barrier (4 x {3 DS_READ, 8 MFMA}). Frag regs P/Q dbuf.
#define TILE1(tt, BUF, FRa, FRb, FWa, FWb)                                   \
  {                                                                          \
    const int kt3 = ((tt) + 3) & (NT32 - 1);                                 \
    PSTG(kt3, (((BUF) + 3) & 3) * 32768);                                    \
    asm volatile("s_waitcnt vmcnt(8)" ::: "memory");                         \
    __builtin_amdgcn_s_barrier();                                            \
    asm volatile("s_waitcnt lgkmcnt(0)" ::: "memory");                       \
    __builtin_amdgcn_sched_barrier(0);                                       \
    const char* const Ln = lds + (((BUF) + 1) & 3) * 32768;                  \
    __builtin_amdgcn_s_setprio(1);                                           \
    UNR for (int mi = 0; mi < 8; ++mi)                                       \
      FWa[mi] = *(const bf16x8*)(Ln + (wm * 8 + mi) * 1024 + lofs);          \
    UNR for (int ni = 0; ni < 4; ++ni)                                       \
      FWb[ni] = *(const bf16x8*)(Ln + 16384 + (wn * 4 + ni) * 1024 + lofs);  \
    UNR for (int mi = 0; mi < 8; ++mi)                                       \
      UNR for (int ni = 0; ni < 4; ++ni)                                     \
        acc[mi][ni] = __builtin_amdgcn_mfma_f32_16x16x32_bf16(               \
            FRa[mi], FRb[ni], acc[mi][ni], 0, 0, 0);                         \
    UNR for (int gph = 0; gph < 4; ++gph) {                                  \
      __builtin_amdgcn_sched_group_barrier(0x100, 3, 0);  /* 3 DS_READ */    \
      __builtin_amdgcn_sched_group_barrier(0x008, 8, 0);  /* 8 MFMA    */    \
    }                                                                        \
    __builtin_amdgcn_s_setprio(0);                                           \
  }

__global__ __launch_bounds__(512, 2) void fused_kernel(KParams p) {
  __shared__ __align__(16) char lds[131072];

  const int tid = threadIdx.x;
  const int w = tid >> 6, l = tid & 63;

  // ================= phase 1: pack fp32 -> bf16 (A = concat(x,h), W) ======
  {
    const int gtid = blockIdx.x * 512 + tid;   // 131072 threads
#pragma unroll 2
    for (int i = 0; i < 16; ++i) {
      const int idx = gtid + i * 131072;
      const int e = idx * 4;
      const int row = e >> 11, col = e & 2047;
      const float* src = (col < 1024)
                             ? (p.x + (size_t)row * 1024 + col)
                             : (p.h + (size_t)row * 1024 + (col - 1024));
      float4 v = *(const float4*)src;
      ushort4 o;
      o.x = f2bf(v.x); o.y = f2bf(v.y); o.z = f2bf(v.z); o.w = f2bf(v.w);
      *(ushort4*)(p.Abf + e) = o;
    }
#pragma unroll 2
    for (int i = 0; i < 16; ++i) {
      const int e = (gtid + i * 131072) * 4;
      float4 v = *(const float4*)(p.W + e);
      ushort4 o;
      o.x = f2bf(v.x); o.y = f2bf(v.y); o.z = f2bf(v.z); o.w = f2bf(v.w);
      *(ushort4*)(p.Wbf + e) = o;
    }
  }
  cg::this_grid().sync();

  // ================= phase 2: GEMM 256x256, BK=32, 4-buf, 1 barrier/tile ==
  {
    const unsigned short* __restrict__ A = p.Abf;
    const unsigned short* __restrict__ Wb = p.Wbf;
    const int wm = w >> 2, wn = w & 3;          // 2 x 4 wave grid

    // XCD-aware swizzle: 256 blocks, 8 XCDs, each owns a 4x8 rect.
    const int bid = blockIdx.x;
    const int xcd = bid & 7, li = bid >> 3;
    const int by = (xcd & 3) * 4 + (li >> 3);
    const int bx = ((xcd >> 2) << 3) + (li & 7);
    const int bm = by * 256, bn = bx * 256;

    // swizzled ds_read lane offset within a 1KB subtile (16 rows x 32 bf16)
    const int lofs = (((l & 15) * 64) + ((l >> 4) * 16)) ^ ((l & 8) << 2);
    // inverse-swizzle lane mapping for linear global_load_lds staging
    const int lane_r = (l >> 2) & 15;
    const int lane_c = ((l & 3) * 8) ^ (((l >> 5) & 1) * 16);

    const int dstOfs = w * 2048;
    const unsigned short* gAw =
        A + (size_t)(bm + 32 * w + lane_r) * K_DIM + lane_c;
    const unsigned short* gBw =
        Wb + (size_t)(bn + 32 * w + lane_r) * K_DIM + lane_c;

    f32x4 acc[8][4];
#pragma unroll
    for (int i = 0; i < 8; ++i)
#pragma unroll
      for (int j = 0; j < 4; ++j) acc[i][j] = (f32x4)0.0f;

    // prologue: stage tiles 0,1,2 into buf 0,1,2; read frags(0)
    PSTG(0, 0);
    PSTG(1, 32768);
    PSTG(2, 65536);
    asm volatile("s_waitcnt vmcnt(8)" ::: "memory");   // tile0 landed
    __builtin_amdgcn_s_barrier();

    bf16x8 aP[8], bP[4], aQ[8], bQ[4];
#pragma unroll
    for (int mi = 0; mi < 8; ++mi)
      aP[mi] = *(const bf16x8*)(lds + (wm * 8 + mi) * 1024 + lofs);
#pragma unroll
    for (int ni = 0; ni < 4; ++ni)
      bP[ni] = *(const bf16x8*)(lds + 16384 + (wn * 4 + ni) * 1024 + lofs);

    for (int t = 0; t < NT32; t += 4) {
      TILE1(t + 0, 0, aP, bP, aQ, bQ);
      TILE1(t + 1, 1, aQ, bQ, aP, bP);
      TILE1(t + 2, 2, aP, bP, aQ, bQ);
      TILE1(t + 3, 3, aQ, bQ, aP, bP);
    }

    // epilogue: +bias (fp32), convert to bf16, store gates
    const int lm = l & 15, lq = l >> 4;
    float bv[4];
#pragma unroll
    for (int ni = 0; ni < 4; ++ni)
      bv[ni] = p.bias[bn + wn * 64 + ni * 16 + lm];
    unsigned short* Cb =
        p.gates + (size_t)(bm + wm * 128) * N_DIM + bn + wn * 64;
#pragma unroll
    for (int mi = 0; mi < 8; ++mi)
#pragma unroll
      for (int j = 0; j < 4; ++j) {
        const size_t rofs = (size_t)(mi * 16 + lq * 4 + j) * N_DIM;
#pragma unroll
        for (int ni = 0; ni < 4; ++ni)
          Cb[rofs + ni * 16 + lm] = f2bf(acc[mi][ni][j] + bv[ni]);
      }
  }
  cg::this_grid().sync();

  // ================= phase 3: LN + activations + cell update ==============
  // one wave per row, 2 rows per wave; 16 cols/lane; no LDS, no barriers.
  {
#pragma unroll
    for (int it = 0; it < 2; ++it) {
      const int row = blockIdx.x * 16 + w * 2 + it;
      const unsigned short* grow = p.gates + (size_t)row * N_DIM;
      const int cb = l * 16;

      float av[4][16];
      float s8[8];
#pragma unroll
      for (int g4 = 0; g4 < 4; ++g4) {
        float ss = 0.0f, qq = 0.0f;
#pragma unroll
        for (int u = 0; u < 2; ++u) {
          bf16x8 r = *(const bf16x8*)(grow + g4 * 1024 + cb + u * 8);
#pragma unroll
          for (int j = 0; j < 8; ++j) {
            float f = bf2f((unsigned short)r[j]);
            av[g4][u * 8 + j] = f;
            ss += f; qq += f * f;
          }
        }
        s8[g4] = ss; s8[4 + g4] = qq;
      }
#pragma unroll
      for (int o = 32; o >= 1; o >>= 1)
#pragma unroll
        for (int i = 0; i < 8; ++i) s8[i] += __shfl_xor(s8[i], o, 64);

      const float* gmp[4] = {p.gi, p.gf, p.gg, p.go};
      const float* btp[4] = {p.bi2, p.bf2, p.bg2, p.bo2};
#pragma unroll
      for (int g4 = 0; g4 < 4; ++g4) {
        const float mu = s8[g4] * (1.0f / 1024.0f);
        const float var = s8[4 + g4] * (1.0f / 1024.0f) - mu * mu;
        const float inv = rsqrtf(var + 1e-5f);
        float gm[16], bt[16];
#pragma unroll
        for (int q4 = 0; q4 < 4; ++q4) {
          *(float4*)&gm[q4 * 4] = *(const float4*)(gmp[g4] + cb + q4 * 4);
          *(float4*)&bt[q4 * 4] = *(const float4*)(btp[g4] + cb + q4 * 4);
        }
#pragma unroll
        for (int j = 0; j < 16; ++j) {
          const float n = (av[g4][j] - mu) * inv * gm[j] + bt[j];
          av[g4][j] = (g4 == 2) ? tanhf_(n) : sigmoidf_(n);
        }
      }

      float cn[16];
#pragma unroll
      for (int q4 = 0; q4 < 4; ++q4) {
        float4 cp = *(const float4*)(p.c + (size_t)row * 1024 + cb + q4 * 4);
        const float* cpe = (const float*)&cp;
#pragma unroll
        for (int j = 0; j < 4; ++j) {
          const int e = q4 * 4 + j;
          cn[e] = av[1][e] * cpe[j] + av[0][e] * av[2][e];
        }
      }

      float u0 = 0.0f, u1 = 0.0f;
#pragma unroll
      for (int j = 0; j < 16; ++j) { u0 += cn[j]; u1 += cn[j] * cn[j]; }
#pragma unroll
      for (int o = 32; o >= 1; o >>= 1) {
        u0 += __shfl_xor(u0, o, 64);
        u1 += __shfl_xor(u1, o, 64);
      }
      const float muc = u0 * (1.0f / 1024.0f);
      const float invc = rsqrtf(u1 * (1.0f / 1024.0f) - muc * muc + 1e-5f);

      float* hout = p.out + (size_t)row * 1024 + cb;
      float* cout = p.out + (size_t)B_ROWS * H_DIM + (size_t)row * 1024 + cb;
#pragma unroll
      for (int q4 = 0; q4 < 4; ++q4) {
        float4 gcv = *(const float4*)(p.gc + cb + q4 * 4);
        float4 bcv = *(const float4*)(p.bc2 + cb + q4 * 4);
        const float* gce = (const float*)&gcv;
        const float* bce = (const float*)&bcv;
        float4 hv, cv;
        float* hve = (float*)&hv; float* cve = (float*)&cv;
#pragma unroll
        for (int j = 0; j < 4; ++j) {
          const int e = q4 * 4 + j;
          const float n = (cn[e] - muc) * invc * gce[j] + bce[j];
          hve[j] = av[3][e] * tanhf_(n);
          cve[j] = cn[e];
        }
        *(float4*)(hout + q4 * 4) = hv;
        *(float4*)(cout + q4 * 4) = cv;
      }
    }
  }
}

// ---------------------------------------------------------------------------
extern "C" void kernel_launch(void* const* d_in, const int* in_sizes, int n_in,
                              void* d_out, int out_size, void* d_ws,
                              size_t ws_size, hipStream_t stream) {
  // workspace: A_bf16 (16MB) | W_bf16 (16MB) | gates bf16 (32MB)
  unsigned short* Abf = (unsigned short*)d_ws;
  unsigned short* Wbf = Abf + (size_t)B_ROWS * K_DIM;
  unsigned short* gates = Wbf + (size_t)N_DIM * K_DIM;

  KParams p;
  p.x = (const float*)d_in[0];
  p.h = (const float*)d_in[1];
  p.c = (const float*)d_in[2];
  p.W = (const float*)d_in[3];
  p.bias = (const float*)d_in[4];
  p.gi = (const float*)d_in[5];
  p.bi2 = (const float*)d_in[6];
  p.gf = (const float*)d_in[7];
  p.bf2 = (const float*)d_in[8];
  p.gg = (const float*)d_in[9];
  p.bg2 = (const float*)d_in[10];
  p.go = (const float*)d_in[11];
  p.bo2 = (const float*)d_in[12];
  p.gc = (const float*)d_in[13];
  p.bc2 = (const float*)d_in[14];
  p.Abf = Abf;
  p.Wbf = Wbf;
  p.gates = gates;
  p.out = (float*)d_out;

  void* args[] = {(void*)&p};
  hipLaunchCooperativeKernel((void*)fused_kernel, dim3(256), dim3(512), args,
                             0, stream);
}

// Round 9
// 106.350 us; speedup vs baseline: 1.7440x; 1.7440x over previous
//
#include <hip/hip_runtime.h>
#include <hip/hip_bf16.h>

// Fixed shape: B=4096, I=1024, H=1024
#define B_ROWS 4096
#define H_DIM  1024
#define K_DIM  2048   // I + H
#define N_DIM  4096   // 4H
#define NT32   64     // K_DIM / 32 K-tiles

typedef __attribute__((ext_vector_type(8))) short bf16x8;
typedef __attribute__((ext_vector_type(4))) float f32x4;

__device__ __forceinline__ unsigned short f2bf(float f) {
  union { float f; unsigned int u; } v; v.f = f;
  unsigned int u = v.u;
  return (unsigned short)((u + 0x7fffu + ((u >> 16) & 1u)) >> 16);
}
__device__ __forceinline__ float bf2f(unsigned short u) {
  union { unsigned int u; float f; } v; v.u = ((unsigned int)u) << 16;
  return v.f;
}

__device__ __forceinline__ void gload_lds16(const void* g, void* l) {
  __builtin_amdgcn_global_load_lds(
      (const __attribute__((address_space(1))) void*)g,
      (__attribute__((address_space(3))) void*)l, 16, 0, 0);
}

// -------- merged pack kernel: fp32 -> bf16 for A=concat(x,h) and W ---------
__global__ __launch_bounds__(256) void pack_kernel(
    const float* __restrict__ x, const float* __restrict__ h,
    const float* __restrict__ W, unsigned short* __restrict__ Abf,
    unsigned short* __restrict__ Wbf) {
  int bid = blockIdx.x;
  if (bid < 8192) {
    int t = bid * 256 + threadIdx.x;
    int e = t * 4;
    int row = e >> 11;
    int col = e & 2047;
    const float* src = (col < 1024) ? (x + (size_t)row * 1024 + col)
                                    : (h + (size_t)row * 1024 + (col - 1024));
    float4 v = *(const float4*)src;
    ushort4 o;
    o.x = f2bf(v.x); o.y = f2bf(v.y); o.z = f2bf(v.z); o.w = f2bf(v.w);
    *(ushort4*)(Abf + e) = o;
  } else {
    int t = (bid - 8192) * 256 + threadIdx.x;
    int e = t * 4;
    float4 v = *(const float4*)(W + e);
    ushort4 o;
    o.x = f2bf(v.x); o.y = f2bf(v.y); o.z = f2bf(v.z); o.w = f2bf(v.w);
    *(ushort4*)(Wbf + e) = o;
  }
}

// -------- GEMM: 256x256, BK=32, 4-buf, 1 barrier/tile, 16 waves ------------
// gates(bf16) = A(4096x2048 bf16) * W^T(4096x2048 bf16) + bias(fp32)
// 1024 threads = 16 waves, wave grid 4x4, wave-tile 64x64 (16 MFMA 16x16x32,
// acc = 64 VGPR) -> combined regs ~120 -> 4 waves/SIMD occupancy; frag reads
// single-buffered post-barrier, latency hidden by 3 co-resident waves/SIMD.
// LDS = 4 x 32KB buffers (A 16KB + B 16KB; 16x32-bf16 subtiles of 1KB,
// st_16x32 swizzle via pre-swizzled global source + swizzled ds_read).
// Per tile t: stage(t+2 -> buf[(t+2)&3], 2 gloads/wave) -> vmcnt(2) ->
// barrier -> 8 ds_read frags(t) -> lgkmcnt(0) -> 16 MFMA.
// Race-free: laggards at phase t-1 read buf[(t-1)&3] != buf[(t+2)&3].

#define UNR _Pragma("unroll")

#define PSTG(kt, BUFOFS)                                                     \
  {                                                                          \
    const size_t ko = (size_t)(kt) << 5;                                     \
    char* const Ld = lds + (BUFOFS);                                         \
    gload_lds16(gAw + ko, Ld + dstOfs);                                      \
    gload_lds16(gBw + ko, Ld + 16384 + dstOfs);                              \
  }

#define TILE1(tt, BUF)                                                       \
  {                                                                          \
    const int kt2 = ((tt) + 2) & (NT32 - 1);                                 \
    PSTG(kt2, (((BUF) + 2) & 3) * 32768);                                    \
    asm volatile("s_waitcnt vmcnt(2)" ::: "memory");                         \
    __builtin_amdgcn_s_barrier();                                            \
    const char* const Lc = lds + (BUF) * 32768;                              \
    bf16x8 aF[4], bF[4];                                                     \
    UNR for (int mi = 0; mi < 4; ++mi)                                       \
      aF[mi] = *(const bf16x8*)(Lc + (wm * 4 + mi) * 1024 + lofs);           \
    UNR for (int ni = 0; ni < 4; ++ni)                                       \
      bF[ni] = *(const bf16x8*)(Lc + 16384 + (wn * 4 + ni) * 1024 + lofs);   \
    asm volatile("s_waitcnt lgkmcnt(0)" ::: "memory");                       \
    __builtin_amdgcn_sched_barrier(0);                                       \
    __builtin_amdgcn_s_setprio(1);                                           \
    UNR for (int mi = 0; mi < 4; ++mi)                                       \
      UNR for (int ni = 0; ni < 4; ++ni)                                     \
        acc[mi][ni] = __builtin_amdgcn_mfma_f32_16x16x32_bf16(               \
            aF[mi], bF[ni], acc[mi][ni], 0, 0, 0);                           \
    __builtin_amdgcn_s_setprio(0);                                           \
  }

__global__ __launch_bounds__(1024, 4) void gemm_kernel(
    const unsigned short* __restrict__ A, const unsigned short* __restrict__ W,
    const float* __restrict__ bias, unsigned short* __restrict__ C) {
  __shared__ __align__(16) char lds[131072];

  const int tid = threadIdx.x;
  const int w = tid >> 6, l = tid & 63;
  const int wm = w >> 2, wn = w & 3;            // 4 x 4 wave grid

  // XCD-aware swizzle: 256 blocks, 8 XCDs, each XCD owns a 4x8 rect.
  const int bid = blockIdx.x;
  const int xcd = bid & 7, li = bid >> 3;
  const int by = (xcd & 3) * 4 + (li >> 3);
  const int bx = ((xcd >> 2) << 3) + (li & 7);
  const int bm = by * 256, bn = bx * 256;

  // swizzled ds_read lane offset within a 1KB subtile (16 rows x 32 bf16)
  const int lofs = (((l & 15) * 64) + ((l >> 4) * 16)) ^ ((l & 8) << 2);
  // inverse-swizzle lane mapping for linear global_load_lds staging
  const int lane_r = (l >> 2) & 15;
  const int lane_c = ((l & 3) * 8) ^ (((l >> 5) & 1) * 16);

  // wave w stages A rows 16w..16w+15 and B rows 16w..16w+15 (1 subtile each)
  const int dstOfs = w * 1024;
  const unsigned short* gAw = A + (size_t)(bm + 16 * w + lane_r) * K_DIM + lane_c;
  const unsigned short* gBw = W + (size_t)(bn + 16 * w + lane_r) * K_DIM + lane_c;

  f32x4 acc[4][4];
#pragma unroll
  for (int i = 0; i < 4; ++i)
#pragma unroll
    for (int j = 0; j < 4; ++j) acc[i][j] = (f32x4)0.0f;

  // ---- prologue: stage tiles 0,1 into buf 0,1 ----
  PSTG(0, 0);
  PSTG(1, 32768);

  for (int t = 0; t < NT32; t += 4) {
    TILE1(t + 0, 0);
    TILE1(t + 1, 1);
    TILE1(t + 2, 2);
    TILE1(t + 3, 3);
  }

  // ---- epilogue: +bias (fp32), convert to bf16, store ----
  const int lm = l & 15, lq = l >> 4;
  float bv[4];
#pragma unroll
  for (int ni = 0; ni < 4; ++ni) bv[ni] = bias[bn + wn * 64 + ni * 16 + lm];
  unsigned short* Cb = C + (size_t)(bm + wm * 64) * N_DIM + bn + wn * 64;
#pragma unroll
  for (int mi = 0; mi < 4; ++mi)
#pragma unroll
    for (int j = 0; j < 4; ++j) {
      const size_t rofs = (size_t)(mi * 16 + lq * 4 + j) * N_DIM;
#pragma unroll
      for (int ni = 0; ni < 4; ++ni)
        Cb[rofs + ni * 16 + lm] = f2bf(acc[mi][ni][j] + bv[ni]);
    }
}

// -------- fused LN + activations + cell update -----------------------------
__device__ __forceinline__ float sigmoidf_(float x) {
  return 1.0f / (1.0f + __expf(-x));
}
__device__ __forceinline__ float tanhf_(float x) {
  return 1.0f - 2.0f / (__expf(2.0f * x) + 1.0f);
}

__global__ __launch_bounds__(256) void ln_lstm_kernel(
    const unsigned short* __restrict__ gates, const float* __restrict__ cprev,
    const float* __restrict__ g_i, const float* __restrict__ b_i,
    const float* __restrict__ g_f, const float* __restrict__ b_f,
    const float* __restrict__ g_g, const float* __restrict__ b_g,
    const float* __restrict__ g_o, const float* __restrict__ b_o,
    const float* __restrict__ g_c, const float* __restrict__ b_c,
    float* __restrict__ out) {
  const int b = blockIdx.x;
  const int t = threadIdx.x;
  const int wid = t >> 6, lane = t & 63;
  __shared__ float red[32];

  const unsigned short* grow = gates + (size_t)b * N_DIM;
  const int c0 = t * 4;

  float v[4][4];
#pragma unroll
  for (int g = 0; g < 4; g++) {
    ushort4 raw = *(const ushort4*)(grow + g * 1024 + c0);
    v[g][0] = bf2f(raw.x); v[g][1] = bf2f(raw.y);
    v[g][2] = bf2f(raw.z); v[g][3] = bf2f(raw.w);
  }

  const float4 gamma[4] = {*(const float4*)(g_i + c0), *(const float4*)(g_f + c0),
                           *(const float4*)(g_g + c0), *(const float4*)(g_o + c0)};
  const float4 beta[4]  = {*(const float4*)(b_i + c0), *(const float4*)(b_f + c0),
                           *(const float4*)(b_g + c0), *(const float4*)(b_o + c0)};

  // batched reduce: 4 sums + 4 sumsqs in one pass
  float s[8];
#pragma unroll
  for (int g = 0; g < 4; g++) {
    s[g]     = v[g][0] + v[g][1] + v[g][2] + v[g][3];
    s[4 + g] = v[g][0]*v[g][0] + v[g][1]*v[g][1] + v[g][2]*v[g][2] + v[g][3]*v[g][3];
  }
#pragma unroll
  for (int o = 32; o >= 1; o >>= 1)
#pragma unroll
    for (int i = 0; i < 8; i++) s[i] += __shfl_xor(s[i], o, 64);
  if (lane == 0) {
#pragma unroll
    for (int i = 0; i < 8; i++) red[wid * 8 + i] = s[i];
  }
  __syncthreads();
#pragma unroll
  for (int i = 0; i < 8; i++) s[i] = red[i] + red[8 + i] + red[16 + i] + red[24 + i];

  float a[4][4];
#pragma unroll
  for (int g = 0; g < 4; g++) {
    float mu = s[g] * (1.0f / 1024.0f);
    float var = s[4 + g] * (1.0f / 1024.0f) - mu * mu;
    float inv = rsqrtf(var + 1e-5f);
    const float* gm = (const float*)&gamma[g];
    const float* bt = (const float*)&beta[g];
#pragma unroll
    for (int j = 0; j < 4; j++) {
      float n = (v[g][j] - mu) * inv * gm[j] + bt[j];
      a[g][j] = (g == 2) ? tanhf_(n) : sigmoidf_(n);
    }
  }

  float4 cp = *(const float4*)(cprev + (size_t)b * 1024 + c0);
  const float* cpe = (const float*)&cp;
  float cn[4];
#pragma unroll
  for (int j = 0; j < 4; j++)
    cn[j] = a[1][j] * cpe[j] + a[0][j] * a[2][j];

  {
    float u0 = cn[0] + cn[1] + cn[2] + cn[3];
    float u1 = cn[0]*cn[0] + cn[1]*cn[1] + cn[2]*cn[2] + cn[3]*cn[3];
#pragma unroll
    for (int o = 32; o >= 1; o >>= 1) {
      u0 += __shfl_xor(u0, o, 64);
      u1 += __shfl_xor(u1, o, 64);
    }
    __syncthreads();   // all reads of red (round 1) done before overwrite
    if (lane == 0) { red[wid * 2] = u0; red[wid * 2 + 1] = u1; }
    __syncthreads();
    u0 = red[0] + red[2] + red[4] + red[6];
    u1 = red[1] + red[3] + red[5] + red[7];
    float mu = u0 * (1.0f / 1024.0f);
    float var = u1 * (1.0f / 1024.0f) - mu * mu;
    float inv = rsqrtf(var + 1e-5f);
    float4 gm = *(const float4*)(g_c + c0);
    float4 bt = *(const float4*)(b_c + c0);
    const float* gme = (const float*)&gm;
    const float* bte = (const float*)&bt;
    float hn[4];
#pragma unroll
    for (int j = 0; j < 4; j++) {
      float n = (cn[j] - mu) * inv * gme[j] + bte[j];
      hn[j] = a[3][j] * tanhf_(n);
    }
    *(float4*)(out + (size_t)b * 1024 + c0) = make_float4(hn[0], hn[1], hn[2], hn[3]);
    *(float4*)(out + (size_t)B_ROWS * H_DIM + (size_t)b * 1024 + c0) =
        make_float4(cn[0], cn[1], cn[2], cn[3]);
  }
}

// ---------------------------------------------------------------------------
extern "C" void kernel_launch(void* const* d_in, const int* in_sizes, int n_in,
                              void* d_out, int out_size, void* d_ws,
                              size_t ws_size, hipStream_t stream) {
  const float* x    = (const float*)d_in[0];
  const float* h    = (const float*)d_in[1];
  const float* c    = (const float*)d_in[2];
  const float* W    = (const float*)d_in[3];
  const float* bias = (const float*)d_in[4];
  const float* ln_i_g = (const float*)d_in[5];
  const float* ln_i_b = (const float*)d_in[6];
  const float* ln_f_g = (const float*)d_in[7];
  const float* ln_f_b = (const float*)d_in[8];
  const float* ln_g_g = (const float*)d_in[9];
  const float* ln_g_b = (const float*)d_in[10];
  const float* ln_o_g = (const float*)d_in[11];
  const float* ln_o_b = (const float*)d_in[12];
  const float* ln_c_g = (const float*)d_in[13];
  const float* ln_c_b = (const float*)d_in[14];

  // workspace: A_bf16 (16MB) | W_bf16 (16MB) | gates bf16 (32MB)
  unsigned short* Abf = (unsigned short*)d_ws;
  unsigned short* Wbf = Abf + (size_t)B_ROWS * K_DIM;
  unsigned short* gates = Wbf + (size_t)N_DIM * K_DIM;

  pack_kernel<<<16384, 256, 0, stream>>>(x, h, W, Abf, Wbf);

  dim3 ggrid(256);
  gemm_kernel<<<ggrid, 1024, 0, stream>>>(Abf, Wbf, bias, gates);

  ln_lstm_kernel<<<B_ROWS, 256, 0, stream>>>(
      gates, c, ln_i_g, ln_i_b, ln_f_g, ln_f_b, ln_g_g, ln_g_b,
      ln_o_g, ln_o_b, ln_c_g, ln_c_b, (float*)d_out);
}